// Round 13
// baseline (48.205 us; speedup 1.0000x reference)
//
#include <hip/hip_runtime.h>
#include <hip/hip_fp16.h>
#include <math.h>

#define TT 8192
#define FF 64
#define TILE 16
#define HALO 50
#define ROWS (TILE + HALO)   // 66
#define XPAD 72              // f16 row stride (144B = 36 banks -> column reads spread)
#define TSTR 68              // f32 plane row stride (272B, 16B-aligned rows)

typedef float f32x4 __attribute__((ext_vector_type(4)));
typedef _Float16 f16x8 __attribute__((ext_vector_type(8)));
typedef unsigned int u32x4 __attribute__((ext_vector_type(4)));
typedef unsigned int u32x2 __attribute__((ext_vector_type(2)));

__device__ __forceinline__ float rcpf(float x) { return __builtin_amdgcn_rcpf(x); }

// ---- prep: wsmH[j*64+i] = f16 softmax(W)[i][j]; pwB = f16 MFMA B-frags of PW ----
// B-frag (mfma_f32_16x16x32_f16): lane holds B[k=(lane>>4)*8+q][col=lane&15],
// B[k][col] = PW[n*16+col][k]; slot (n*2+kt)*64+lane.  (validated in R12)
__global__ void prep_kernel(const float* __restrict__ W, const float* __restrict__ PW,
                            __half* __restrict__ wsmH, u32x4* __restrict__ pwB) {
    const int lane = threadIdx.x;   // j
    const int wv   = threadIdx.y;   // 0..3
    const int tid  = wv * 64 + lane;
    for (int it = 0; it < 16; ++it) {
        const int r = wv * 16 + it; // i
        float v = W[r * 64 + lane];
        float m = v;
        #pragma unroll
        for (int off = 32; off >= 1; off >>= 1)
            m = fmaxf(m, __shfl_xor(m, off, 64));
        float e = __expf(v - m);
        float s = e;
        #pragma unroll
        for (int off = 32; off >= 1; off >>= 1)
            s += __shfl_xor(s, off, 64);
        wsmH[lane * 64 + r] = __float2half(e * rcpf(s));
    }
    for (int s = tid; s < 512; s += 256) {
        const int n2 = s >> 6;
        const int ln = s & 63;
        const int i  = (n2 >> 1) * 16 + (ln & 15);
        const int k0 = (n2 & 1) * 32 + (ln >> 4) * 8;
        u32x4 frag;
        #pragma unroll
        for (int w = 0; w < 4; ++w) {
            const unsigned lo = __half_as_ushort(__float2half_rn(PW[i * 64 + k0 + 2 * w]));
            const unsigned hi = __half_as_ushort(__float2half_rn(PW[i * 64 + k0 + 2 * w + 1]));
            frag[w] = lo | (hi << 16);
        }
        pwB[s] = frag;
    }
}

// ---- fused main: 256 thr / 4 waves, 16-row tile, 8 blocks/CU = 32 waves/CU ----
__global__ __launch_bounds__(256, 8)
void mcao_main(const float* __restrict__ x,
               const __half* __restrict__ wsmH,
               const u32x4* __restrict__ pwB,
               const float* __restrict__ pb,
               const float* __restrict__ kap,
               const float* __restrict__ coeffs,
               float* __restrict__ out,
               float* __restrict__ memout) {
    // LDS 17696 B total -> 9 blocks/CU capacity (grid needs 8, with margin):
    //   [0, 9504)      xsH f16 [66][72]             (until bar2)
    //   [0, 4352)      tS  f32 [16][68]             (after bar2)
    //   [4352, 8704)   uS  f32 [16][68]
    //   [9504, 17696)  wS  f16 [64][64]             (until bar4)
    //   [9504, 13856)  P2  f32 [64][17]             (after bar4)
    __shared__ __align__(16) char smem[17696];
    __half* xsH = (__half*)smem;
    float*  tS  = (float*)smem;
    float*  uS  = (float*)(smem + 4352);
    __half* wS  = (__half*)(smem + 9504);
    float*  P2  = (float*)(smem + 9504);

    const int tid  = threadIdx.x;
    const int lane = tid & 63;
    const int wv   = tid >> 6;              // 0..3

    // XCD-aware bijective swizzle: 2048 blocks -> 256 consecutive tiles per XCD
    const int sw = ((int)blockIdx.x & 7) * 256 + ((int)blockIdx.x >> 3);
    const int b  = sw >> 9;                 // 0..3
    const int t0 = (sw & 511) * TILE;
    const float* xb = x + (size_t)b * TT * FF;

    // ---- stage xsH rows [t0-50, t0+16) as f16 (zero-pad t<0), and wS ----
    for (int i4 = tid; i4 < ROWS * 16; i4 += 256) {
        const int s = i4 >> 4, f4 = i4 & 15, t = t0 - HALO + s;
        f32x4 v = {0.f, 0.f, 0.f, 0.f};
        if (t >= 0) v = *(const f32x4*)(xb + (size_t)t * 64 + f4 * 4);
        __half hv[4];
        #pragma unroll
        for (int q = 0; q < 4; ++q) hv[q] = __float2half_rn(v[q]);
        *(u32x2*)(&xsH[s * XPAD + f4 * 4]) = *(u32x2*)hv;
    }
    ((f32x4*)wS)[tid]       = ((const f32x4*)wsmH)[tid];
    ((f32x4*)wS)[tid + 256] = ((const f32x4*)wsmH)[tid + 256];
    __syncthreads();                                    // bar1

    // ---- FIR: wave owns rows 4wv..4wv+3 (lane = feature) ----
    float macc[4] = {0.f, 0.f, 0.f, 0.f};
    #pragma unroll
    for (int s = 0; s < 54; ++s) {
        const float xv = __half2float(xsH[(4 * wv + s) * XPAD + lane]);
        #pragma unroll
        for (int r = 0; r < 4; ++r) {
            const int k = r + 50 - s;
            if (0 <= k && k <= 50) macc[r] = fmaf(coeffs[k], xv, macc[r]);
        }
    }
    #pragma unroll
    for (int r = 0; r < 4; ++r)
        memout[(size_t)(b * TT + t0 + 4 * wv + r) * 64 + lane] = macc[r];

    // ---- proj via MFMA: M=16 rows, wave wv = N-tile (cols 16wv..16wv+15) ----
    const int arow = lane & 15, kg = lane >> 4;
    f32x4 cfr = {0.f, 0.f, 0.f, 0.f};
    #pragma unroll
    for (int kt = 0; kt < 2; ++kt) {
        const f16x8 afr = *(const f16x8*)(&xsH[(HALO + arow) * XPAD + kt * 32 + kg * 8]);
        const f16x8 bfr = __builtin_bit_cast(f16x8, pwB[(wv * 2 + kt) * 64 + lane]);
        cfr = __builtin_amdgcn_mfma_f32_16x16x32_f16(afr, bfr, cfr, 0, 0, 0);
    }

    // ---- extraction: thread -> (erow=tid>>4, feats (tid&15)*4..+3) ----
    const int erow = tid >> 4, f0 = (tid & 15) * 4;
    const u32x2 raw = *(const u32x2*)(&xsH[(HALO + erow) * XPAD + f0]);
    __half hx[4];
    *(u32x2*)hx = raw;
    f32x4 tq, uq;
    #pragma unroll
    for (int q = 0; q < 4; ++q) {
        const float xi = __half2float(hx[q]);
        tq[q] = fmaf(-2.f, rcpf(__expf(2.f * xi) + 1.f), 1.f);  // tanh
        uq[q] = __expf(-fabsf(xi));                             // e^-|x|
    }
    __syncthreads();                                    // bar2 (xsH dead)
    *(f32x4*)(&tS[erow * TSTR + f0]) = tq;
    *(f32x4*)(&uS[erow * TSTR + f0]) = uq;
    __syncthreads();                                    // bar3

    // ---- coupling: lane = (g=lane>>4, r=lane&15); feats ib..ib+3, row r ----
    const int r  = lane & 15;
    const int g  = lane >> 4;
    const int ib = wv * 16 + g * 4;
    const f32x4 ti = *(const f32x4*)(&tS[r * TSTR + ib]);
    const f32x4 ui = *(const f32x4*)(&uS[r * TSTR + ib]);

    float cacc[4] = {0.f, 0.f, 0.f, 0.f};
    #pragma unroll 4
    for (int j = 0; j < 64; ++j) {
        const float tj = tS[r * TSTR + j];              // 16-addr 4-lane broadcast: free
        const float uj = uS[r * TSTR + j];
        __half wh[4];
        *(u32x2*)wh = *(const u32x2*)(&wS[j * 64 + ib]); // 4-addr b64 broadcast: free
        #pragma unroll
        for (int q = 0; q < 4; ++q) {
            const float d1 = fmaf(-ti[q], tj, 1.f);     // 1 - ti*tj
            const float d2 = fmaf( ui[q], uj, 1.f);     // 1 + ui*uj
            const float rr = rcpf(d1 * d2);
            cacc[q] = fmaf(__half2float(wh[q]), (ti[q] - tj) * rr, cacc[q]); // fma_mix
        }
    }
    __syncthreads();                                    // bar4 (wS dead)

    // ---- proj C-frag -> P2 (wave-private region; in-wave ordering, no barrier) ----
    {
        const int ic = wv * 16 + (lane & 15);
        const int rb = (lane >> 4) * 4;
        #pragma unroll
        for (int reg = 0; reg < 4; ++reg)
            P2[ic * 17 + rb + reg] = cfr[reg];
    }
    // ---- epilogue RMW: val = 0.4c + 0.3(proj+pb)ksum (same wave-private slots) ----
    const float kappa = kap[0];
    const float ksum  = (1.f - __expf(-kappa * (float)(t0 + r + 1))) *
                        rcpf(1.f - __expf(-kappa));
    const f32x4 pbv = *(const f32x4*)(pb + ib);
    #pragma unroll
    for (int q = 0; q < 4; ++q) {
        const int idx = (ib + q) * 17 + r;
        P2[idx] = fmaf(0.4f, cacc[q], 0.3f * (P2[idx] + pbv[q]) * ksum);
    }
    __syncthreads();                                    // bar5 (cross-wave P2 reads)

    // ---- final store: wave rows 4wv..4wv+3, lane = feature (coalesced) ----
    #pragma unroll
    for (int rr2 = 0; rr2 < 4; ++rr2) {
        const int row = 4 * wv + rr2;
        out[(size_t)(b * TT + t0 + row) * 64 + lane] =
            fmaf(0.3f, macc[rr2], P2[lane * 17 + row]);  // 17*lane%32 bijective: free
    }
}

extern "C" void kernel_launch(void* const* d_in, const int* in_sizes, int n_in,
                              void* d_out, int out_size, void* d_ws, size_t ws_size,
                              hipStream_t stream) {
    const float* x   = (const float*)d_in[0];
    const float* W   = (const float*)d_in[1];
    const float* PW  = (const float*)d_in[2];
    const float* pb  = (const float*)d_in[3];
    const float* kap = (const float*)d_in[4];
    const float* cf  = (const float*)d_in[5];

    float* out    = (float*)d_out;
    float* memout = out + (size_t)4 * TT * FF;

    __half* wsmH = (__half*)d_ws;                        // 8 KB
    u32x4*  pwB  = (u32x4*)((char*)d_ws + 8192);         // 8 KB

    hipLaunchKernelGGL(prep_kernel, dim3(1), dim3(64, 4), 0, stream, W, PW, wsmH, pwB);
    hipLaunchKernelGGL(mcao_main, dim3(4 * (TT / TILE)), dim3(256), 0, stream,
                       x, wsmH, pwB, pb, kap, cf, out, memout);
}

// Round 14
// 45.228 us; speedup vs baseline: 1.0658x; 1.0658x over previous
//
#include <hip/hip_runtime.h>
#include <hip/hip_fp16.h>
#include <math.h>

#define TT 8192
#define FF 64
#define TILE 32
#define HALO 50
#define ROWS (TILE + HALO)   // 82
#define XSTR 72              // f16 row stride for xsH

typedef float f32x2 __attribute__((ext_vector_type(2)));
typedef float f32x4 __attribute__((ext_vector_type(4)));
typedef _Float16 f16x8 __attribute__((ext_vector_type(8)));
typedef unsigned int u32x4 __attribute__((ext_vector_type(4)));
typedef unsigned int u32x2 __attribute__((ext_vector_type(2)));

__device__ __forceinline__ float rcpf(float x) { return __builtin_amdgcn_rcpf(x); }

// ---- prep: wsmH[j*64+i] = f16 softmax(W)[i][j]; pwB = f16 MFMA B-frags of PW ----
// B-frag (mfma_f32_16x16x32_f16): lane holds B[k=(lane>>4)*8+q][col=lane&15],
// B[k][col] = PW[n*16+col][k]; slot (n*2+kt)*64+lane.  (validated R12/R13)
__global__ void prep_kernel(const float* __restrict__ W, const float* __restrict__ PW,
                            __half* __restrict__ wsmH, u32x4* __restrict__ pwB) {
    const int lane = threadIdx.x;
    const int wv   = threadIdx.y;
    const int tid  = wv * 64 + lane;
    for (int it = 0; it < 16; ++it) {
        const int r = wv * 16 + it;
        float v = W[r * 64 + lane];
        float m = v;
        #pragma unroll
        for (int off = 32; off >= 1; off >>= 1)
            m = fmaxf(m, __shfl_xor(m, off, 64));
        float e = __expf(v - m);
        float s = e;
        #pragma unroll
        for (int off = 32; off >= 1; off >>= 1)
            s += __shfl_xor(s, off, 64);
        wsmH[lane * 64 + r] = __float2half(e * rcpf(s));
    }
    for (int s = tid; s < 512; s += 256) {
        const int n2 = s >> 6;
        const int ln = s & 63;
        const int i  = (n2 >> 1) * 16 + (ln & 15);
        const int k0 = (n2 & 1) * 32 + (ln >> 4) * 8;
        u32x4 frag;
        #pragma unroll
        for (int w = 0; w < 4; ++w) {
            const unsigned lo = __half_as_ushort(__float2half_rn(PW[i * 64 + k0 + 2 * w]));
            const unsigned hi = __half_as_ushort(__float2half_rn(PW[i * 64 + k0 + 2 * w + 1]));
            frag[w] = lo | (hi << 16);
        }
        pwB[s] = frag;
    }
}

// ---- fused main: 512 thr / 8 waves, 32-row tile, 4 blocks/CU = 32 waves/CU ----
__global__ __launch_bounds__(512, 8)
void mcao_main(const float* __restrict__ x,
               const __half* __restrict__ wsmH,
               const u32x4* __restrict__ pwB,
               const float* __restrict__ pb,
               const float* __restrict__ kap,
               const float* __restrict__ coeffs,
               float* __restrict__ out,
               float* __restrict__ memout) {
    // LDS 37408 B -> 4 blocks/CU:
    //   [0, 11808)      xsH f16 [82][72]     (dead after bar2)
    //   [0, 8448)       P2  f32 [64][33]     (after j-loop, overlays xsH)
    //   [11808, 29216)  tuS f32x2 [64][34]   {t,u}[feat][row]
    //   [29216, 37408)  wS  f16 [64][64]
    __shared__ __align__(16) char smem[37408];
    __half* xsH = (__half*)smem;
    float*  P2  = (float*)smem;
    f32x2*  tuS = (f32x2*)(smem + 11808);
    __half* wS  = (__half*)(smem + 29216);

    const int tid  = threadIdx.x;
    const int lane = tid & 63;
    const int wv   = tid >> 6;              // 0..7

    // XCD-aware bijective swizzle: 1024 blocks -> 128 consecutive tiles per XCD
    const int sw = ((int)blockIdx.x & 7) * 128 + ((int)blockIdx.x >> 3);
    const int b  = sw >> 8;                 // 0..3
    const int t0 = (sw & 255) * TILE;
    const float* xb = x + (size_t)b * TT * FF;

    // ---- stage xsH rows [t0-50, t0+32) as f16 (zero-pad t<0), and wS ----
    for (int i4 = tid; i4 < ROWS * 16; i4 += 512) {
        const int s = i4 >> 4, f4 = i4 & 15, t = t0 - HALO + s;
        f32x4 v = {0.f, 0.f, 0.f, 0.f};
        if (t >= 0) v = *(const f32x4*)(xb + (size_t)t * 64 + f4 * 4);
        __half hv[4];
        #pragma unroll
        for (int q = 0; q < 4; ++q) hv[q] = __float2half_rn(v[q]);
        *(u32x2*)(&xsH[s * XSTR + f4 * 4]) = *(u32x2*)hv;
    }
    ((f32x4*)wS)[tid] = ((const f32x4*)wsmH)[tid];
    __syncthreads();                                    // bar1

    // ---- FIR: wave owns rows 4wv..4wv+3 (lane = feature) ----
    float macc[4] = {0.f, 0.f, 0.f, 0.f};
    #pragma unroll
    for (int s = 0; s < 54; ++s) {
        const float xv = __half2float(xsH[(4 * wv + s) * XSTR + lane]);
        #pragma unroll
        for (int r = 0; r < 4; ++r) {
            const int k = r + 50 - s;
            if (0 <= k && k <= 50) macc[r] = fmaf(coeffs[k], xv, macc[r]);
        }
    }
    #pragma unroll
    for (int r = 0; r < 4; ++r)
        memout[(size_t)(b * TT + t0 + 4 * wv + r) * 64 + lane] = macc[r];

    // ---- proj via MFMA: wave -> (mt = wv>>2, nt = wv&3) ----
    const int mt = wv >> 2, nt = wv & 3;
    const int arow = HALO + mt * 16 + (lane & 15);
    const int kcol = (lane >> 4) * 8;
    f32x4 cfr = {0.f, 0.f, 0.f, 0.f};
    #pragma unroll
    for (int kt = 0; kt < 2; ++kt) {
        const f16x8 afr = *(const f16x8*)(&xsH[arow * XSTR + kt * 32 + kcol]);
        const f16x8 bfr = __builtin_bit_cast(f16x8, pwB[(nt * 2 + kt) * 64 + lane]);
        cfr = __builtin_amdgcn_mfma_f32_16x16x32_f16(afr, bfr, cfr, 0, 0, 0);
    }

    // ---- extraction: thread -> (erow=tid>>4, feats (tid&15)*4..+3) ----
    const int erow = tid >> 4, f0 = (tid & 15) * 4;
    __half hx[4];
    *(u32x2*)hx = *(const u32x2*)(&xsH[(HALO + erow) * XSTR + f0]);
    #pragma unroll
    for (int q = 0; q < 4; ++q) {
        const float xi = __half2float(hx[q]);
        f32x2 e;
        e.x = fmaf(-2.f, rcpf(__expf(2.f * xi) + 1.f), 1.f);  // tanh
        e.y = __expf(-fabsf(xi));                             // e^-|x|
        tuS[(f0 + q) * 34 + erow] = e;                        // disjoint from xsH
    }
    __syncthreads();                                    // bar2 (planes ready, xsH dead)

    // ---- coupling: lane = (h=lane>>5, r=lane&31); feats ib..ib+3 ----
    const int r  = lane & 31;
    const int h  = lane >> 5;
    const int ib = wv * 8 + h * 4;
    f32x2 tiP[2], uiP[2];
    #pragma unroll
    for (int q = 0; q < 4; ++q) {
        const f32x2 e = tuS[(ib + q) * 34 + r];
        tiP[q >> 1][q & 1] = e.x;
        uiP[q >> 1][q & 1] = e.y;
    }

    f32x2 cac0 = {0.f, 0.f}, cac1 = {0.f, 0.f};
    const f32x2 one2 = {1.f, 1.f};
    #pragma unroll 8
    for (int j = 0; j < 64; ++j) {
        const f32x2 e = tuS[j * 34 + r];            // b64: (4j+2r)%32, 2-way = free
        __half wh[4];
        *(u32x2*)wh = *(const u32x2*)(&wS[j * 64 + ib]);   // 2-addr b64 broadcast
        const f32x2 tjj = {e.x, e.x}, ujj = {e.y, e.y};
        {
            const f32x2 d1  = __builtin_elementwise_fma(-tiP[0], tjj, one2);
            const f32x2 d2  = __builtin_elementwise_fma( uiP[0], ujj, one2);
            const f32x2 den = d1 * d2;
            f32x2 rr; rr.x = rcpf(den.x); rr.y = rcpf(den.y);
            const f32x2 s = (tiP[0] - tjj) * rr;
            cac0.x = fmaf(__half2float(wh[0]), s.x, cac0.x);   // fma_mix
            cac0.y = fmaf(__half2float(wh[1]), s.y, cac0.y);
        }
        {
            const f32x2 d1  = __builtin_elementwise_fma(-tiP[1], tjj, one2);
            const f32x2 d2  = __builtin_elementwise_fma( uiP[1], ujj, one2);
            const f32x2 den = d1 * d2;
            f32x2 rr; rr.x = rcpf(den.x); rr.y = rcpf(den.y);
            const f32x2 s = (tiP[1] - tjj) * rr;
            cac1.x = fmaf(__half2float(wh[2]), s.x, cac1.x);
            cac1.y = fmaf(__half2float(wh[3]), s.y, cac1.y);
        }
    }

    // ---- proj C-frag -> P2 (xsH dead since bar2; no pre-barrier needed) ----
    {
        const int ic = nt * 16 + (lane & 15);
        const int rb = mt * 16 + (lane >> 4) * 4;
        #pragma unroll
        for (int reg = 0; reg < 4; ++reg)
            P2[ic * 33 + rb + reg] = cfr[reg];
    }
    __syncthreads();                                    // bar3 (proj visible)

    // ---- epilogue RMW: P2 <- 0.4c + 0.3(proj+pb)ksum ----
    const float kappa = kap[0];
    const float ksum  = (1.f - __expf(-kappa * (float)(t0 + r + 1))) *
                        rcpf(1.f - __expf(-kappa));
    const f32x4 pbv = *(const f32x4*)(pb + ib);
    #pragma unroll
    for (int q = 0; q < 4; ++q) {
        const float cv = (q & 1) ? ((q >> 1) ? cac1.y : cac0.y)
                                 : ((q >> 1) ? cac1.x : cac0.x);
        const int idx = (ib + q) * 33 + r;
        P2[idx] = fmaf(0.4f, cv, 0.3f * (P2[idx] + pbv[q]) * ksum);
    }
    __syncthreads();                                    // bar4

    // ---- final store: wave rows 4wv..4wv+3, lane = feature (coalesced) ----
    #pragma unroll
    for (int rr2 = 0; rr2 < 4; ++rr2) {
        const int row = 4 * wv + rr2;
        out[(size_t)(b * TT + t0 + row) * 64 + lane] =
            fmaf(0.3f, macc[rr2], P2[lane * 33 + row]);  // (lane+row)%32: free
    }
}

extern "C" void kernel_launch(void* const* d_in, const int* in_sizes, int n_in,
                              void* d_out, int out_size, void* d_ws, size_t ws_size,
                              hipStream_t stream) {
    const float* x   = (const float*)d_in[0];
    const float* W   = (const float*)d_in[1];
    const float* PW  = (const float*)d_in[2];
    const float* pb  = (const float*)d_in[3];
    const float* kap = (const float*)d_in[4];
    const float* cf  = (const float*)d_in[5];

    float* out    = (float*)d_out;
    float* memout = out + (size_t)4 * TT * FF;

    __half* wsmH = (__half*)d_ws;                        // 8 KB
    u32x4*  pwB  = (u32x4*)((char*)d_ws + 8192);         // 8 KB

    hipLaunchKernelGGL(prep_kernel, dim3(1), dim3(64, 4), 0, stream, W, PW, wsmH, pwB);
    hipLaunchKernelGGL(mcao_main, dim3(4 * (TT / TILE)), dim3(512), 0, stream,
                       x, wsmH, pwB, pb, kap, cf, out, memout);
}